// Round 1
// baseline (14298.779 us; speedup 1.0000x reference)
//
#include <hip/hip_runtime.h>
#include <math.h>

#define Bq 4
#define Tt 2048
#define Dd 512
#define Hh 8
#define Ll 4
#define HIDN 2048
#define DHd 64
#define BT (Bq*Tt)                 // 8192
#define BTD ((size_t)BT*Dd)        // 4194304
#define TQ 4

static __device__ __forceinline__ int is_sep(int t) {
    const unsigned long long w0 = 0xFC00FFFF00002600ULL;
    const unsigned long long w1 = 0x7800000078000001ULL;
    if (t < 64)  return (int)((w0 >> t) & 1ULL);
    if (t < 128) return (int)((w1 >> (t - 64)) & 1ULL);
    return 0;
}

__global__ void embed_kernel(const int* __restrict__ tokens, const float* __restrict__ embed,
                             float* __restrict__ x) {
    size_t idx = (size_t)blockIdx.x * blockDim.x + threadIdx.x;   // over BTD/4 float4
    if (idx >= BTD / 4) return;
    size_t row = idx >> 7;                                        // / (Dd/4)
    int tk = tokens[row];
    tk = tk < 0 ? 0 : (tk > 255 ? 255 : tk);
    const float4* src = (const float4*)(embed + (size_t)tk * Dd);
    ((float4*)x)[idx] = src[idx & 127];
}

__global__ void rope_table_kernel(float* __restrict__ cosb, float* __restrict__ sinb) {
    int idx = blockIdx.x * blockDim.x + threadIdx.x;
    if (idx >= Tt * 32) return;
    int t = idx >> 5, j = idx & 31;
    float inv = powf(10000.0f, -(2.0f * j) / 64.0f);
    float ang = (float)t * inv;
    cosb[idx] = cosf(ang);
    sinb[idx] = sinf(ang);
}

__global__ void rmsnorm_kernel(const float* __restrict__ x, const float* __restrict__ w,
                               float* __restrict__ y) {
    int row = blockIdx.x;
    int tid = threadIdx.x;   // 256
    const float2* xr = (const float2*)(x + (size_t)row * Dd);
    float2 v = xr[tid];
    __shared__ float red[256];
    red[tid] = v.x * v.x + v.y * v.y;
    __syncthreads();
    for (int off = 128; off > 0; off >>= 1) {
        if (tid < off) red[tid] += red[tid + off];
        __syncthreads();
    }
    float scale = rsqrtf(red[0] * (1.0f / Dd) + 1e-6f);
    float2 wv = ((const float2*)w)[tid];
    ((float2*)(y + (size_t)row * Dd))[tid] = make_float2(v.x * scale * wv.x, v.y * scale * wv.y);
}

// C[i,j] = (ADD ? res[i,j] : 0) + sum_k A[i,k]*Bm[j,k]   (both row-major, NT)
template<bool ADD>
__global__ __launch_bounds__(256) void gemm_nt_kernel(
    const float* __restrict__ A, const float* __restrict__ Bm,
    const float* __restrict__ res, float* __restrict__ C,
    int M, int N, int K) {
    __shared__ float As[16][68];
    __shared__ float Bs[16][68];
    int tid = threadIdx.x;
    int tx = tid & 15, ty = tid >> 4;
    int bm = blockIdx.y * 64, bn = blockIdx.x * 64;
    int lrow = tid >> 2;              // 0..63
    int lcol = (tid & 3) << 2;        // 0,4,8,12
    float acc[4][4] = {{0.f}};
    const float* Ab = A + (size_t)(bm + lrow) * K + lcol;
    const float* Bb = Bm + (size_t)(bn + lrow) * K + lcol;
    for (int k0 = 0; k0 < K; k0 += 16) {
        float4 a4 = *(const float4*)(Ab + k0);
        float4 b4 = *(const float4*)(Bb + k0);
        As[lcol + 0][lrow] = a4.x; As[lcol + 1][lrow] = a4.y;
        As[lcol + 2][lrow] = a4.z; As[lcol + 3][lrow] = a4.w;
        Bs[lcol + 0][lrow] = b4.x; Bs[lcol + 1][lrow] = b4.y;
        Bs[lcol + 2][lrow] = b4.z; Bs[lcol + 3][lrow] = b4.w;
        __syncthreads();
        #pragma unroll
        for (int k = 0; k < 16; k++) {
            float av[4], bv[4];
            #pragma unroll
            for (int i = 0; i < 4; i++) av[i] = As[k][(ty << 2) + i];
            #pragma unroll
            for (int j = 0; j < 4; j++) bv[j] = Bs[k][(tx << 2) + j];
            #pragma unroll
            for (int i = 0; i < 4; i++)
                #pragma unroll
                for (int j = 0; j < 4; j++) acc[i][j] = fmaf(av[i], bv[j], acc[i][j]);
        }
        __syncthreads();
    }
    #pragma unroll
    for (int i = 0; i < 4; i++) {
        int r = bm + (ty << 2) + i;
        float4 outv = make_float4(acc[i][0], acc[i][1], acc[i][2], acc[i][3]);
        if (ADD) {
            float4 rv = *(const float4*)(res + (size_t)r * N + bn + (tx << 2));
            outv.x += rv.x; outv.y += rv.y; outv.z += rv.z; outv.w += rv.w;
        }
        *(float4*)(C + (size_t)r * N + bn + (tx << 2)) = outv;
    }
}

// G[i,j] = silu(A@W1^T) * (A@W3^T)
__global__ __launch_bounds__(256) void gemm_swiglu_kernel(
    const float* __restrict__ A, const float* __restrict__ W1,
    const float* __restrict__ W3, float* __restrict__ G,
    int M, int N, int K) {
    __shared__ float As[16][68];
    __shared__ float B1s[16][68];
    __shared__ float B3s[16][68];
    int tid = threadIdx.x;
    int tx = tid & 15, ty = tid >> 4;
    int bm = blockIdx.y * 64, bn = blockIdx.x * 64;
    int lrow = tid >> 2;
    int lcol = (tid & 3) << 2;
    float acc1[4][4] = {{0.f}};
    float acc3[4][4] = {{0.f}};
    const float* Ab = A + (size_t)(bm + lrow) * K + lcol;
    const float* B1b = W1 + (size_t)(bn + lrow) * K + lcol;
    const float* B3b = W3 + (size_t)(bn + lrow) * K + lcol;
    for (int k0 = 0; k0 < K; k0 += 16) {
        float4 a4 = *(const float4*)(Ab + k0);
        float4 b1 = *(const float4*)(B1b + k0);
        float4 b3 = *(const float4*)(B3b + k0);
        As[lcol + 0][lrow] = a4.x; As[lcol + 1][lrow] = a4.y;
        As[lcol + 2][lrow] = a4.z; As[lcol + 3][lrow] = a4.w;
        B1s[lcol + 0][lrow] = b1.x; B1s[lcol + 1][lrow] = b1.y;
        B1s[lcol + 2][lrow] = b1.z; B1s[lcol + 3][lrow] = b1.w;
        B3s[lcol + 0][lrow] = b3.x; B3s[lcol + 1][lrow] = b3.y;
        B3s[lcol + 2][lrow] = b3.z; B3s[lcol + 3][lrow] = b3.w;
        __syncthreads();
        #pragma unroll
        for (int k = 0; k < 16; k++) {
            float av[4], b1v[4], b3v[4];
            #pragma unroll
            for (int i = 0; i < 4; i++) av[i] = As[k][(ty << 2) + i];
            #pragma unroll
            for (int j = 0; j < 4; j++) { b1v[j] = B1s[k][(tx << 2) + j]; b3v[j] = B3s[k][(tx << 2) + j]; }
            #pragma unroll
            for (int i = 0; i < 4; i++)
                #pragma unroll
                for (int j = 0; j < 4; j++) {
                    acc1[i][j] = fmaf(av[i], b1v[j], acc1[i][j]);
                    acc3[i][j] = fmaf(av[i], b3v[j], acc3[i][j]);
                }
        }
        __syncthreads();
    }
    #pragma unroll
    for (int i = 0; i < 4; i++) {
        int r = bm + (ty << 2) + i;
        float4 outv;
        float* po = (float*)&outv;
        #pragma unroll
        for (int j = 0; j < 4; j++) {
            float a1 = acc1[i][j];
            float sig = 1.0f / (1.0f + expf(-a1));
            po[j] = a1 * sig * acc3[i][j];
        }
        *(float4*)(G + (size_t)r * N + bn + (tx << 2)) = outv;
    }
}

__global__ void rope_kernel(float* __restrict__ x, const float* __restrict__ cosb,
                            const float* __restrict__ sinb) {
    int idx = blockIdx.x * blockDim.x + threadIdx.x;   // BT*H*32
    if (idx >= BT * Hh * 32) return;
    int row = idx >> 8;
    int rem = idx & 255;
    int h = rem >> 5, j = rem & 31;
    int t = row & (Tt - 1);
    float c = cosb[(t << 5) + j], s = sinb[(t << 5) + j];
    float2* p = (float2*)(x + (size_t)row * Dd + (h << 6) + (j << 1));
    float2 v = *p;
    *p = make_float2(v.x * c - v.y * s, v.x * s + v.y * c);
}

__global__ __launch_bounds__(256) void attn_kernel(
    const float* __restrict__ q, const float* __restrict__ k,
    const float* __restrict__ v, float* __restrict__ o) {
    int t0 = blockIdx.x * TQ;
    int bh = blockIdx.y;
    int b = bh >> 3, h = bh & 7;
    int tid = threadIdx.x;
    __shared__ float sc[TQ][Tt];
    __shared__ float qs[TQ][DHd];
    __shared__ float red[256];
    __shared__ float mval[TQ], sval[TQ];

    for (int i = tid; i < TQ * DHd; i += 256) {
        int qi = i >> 6, d = i & 63;
        qs[qi][d] = q[(size_t)(b * Tt + t0 + qi) * Dd + (h << 6) + d];
    }
    __syncthreads();

    float lmax[TQ] = {-1e30f, -1e30f, -1e30f, -1e30f};
    for (int s = tid; s < Tt; s += 256) {
        const float4* krow = (const float4*)(k + (size_t)(b * Tt + s) * Dd + (h << 6));
        float dot[TQ] = {0.f, 0.f, 0.f, 0.f};
        #pragma unroll 4
        for (int i4 = 0; i4 < 16; i4++) {
            float4 kv = krow[i4];
            #pragma unroll
            for (int qi = 0; qi < TQ; qi++) {
                dot[qi] += qs[qi][i4 * 4 + 0] * kv.x + qs[qi][i4 * 4 + 1] * kv.y
                         + qs[qi][i4 * 4 + 2] * kv.z + qs[qi][i4 * 4 + 3] * kv.w;
            }
        }
        #pragma unroll
        for (int qi = 0; qi < TQ; qi++) {
            float dd = dot[qi] * 0.125f;
            sc[qi][s] = dd;
            lmax[qi] = fmaxf(lmax[qi], dd);
        }
    }
    for (int qi = 0; qi < TQ; qi++) {
        red[tid] = lmax[qi]; __syncthreads();
        for (int off = 128; off > 0; off >>= 1) {
            if (tid < off) red[tid] = fmaxf(red[tid], red[tid + off]);
            __syncthreads();
        }
        if (tid == 0) mval[qi] = red[0];
        __syncthreads();
    }
    float lsum[TQ] = {0.f, 0.f, 0.f, 0.f};
    for (int s = tid; s < Tt; s += 256) {
        #pragma unroll
        for (int qi = 0; qi < TQ; qi++) {
            float e = expf(sc[qi][s] - mval[qi]);
            sc[qi][s] = e;
            lsum[qi] += e;
        }
    }
    for (int qi = 0; qi < TQ; qi++) {
        red[tid] = lsum[qi]; __syncthreads();
        for (int off = 128; off > 0; off >>= 1) {
            if (tid < off) red[tid] += red[tid + off];
            __syncthreads();
        }
        if (tid == 0) sval[qi] = red[0];
        __syncthreads();
    }
    // phase 2: o[d] = sum_s p[s] * v[s,d]
    int d = tid & 63, g = tid >> 6;
    float accv[TQ] = {0.f, 0.f, 0.f, 0.f};
    for (int s = g; s < Tt; s += 4) {
        float vv = v[(size_t)(b * Tt + s) * Dd + (h << 6) + d];
        #pragma unroll
        for (int qi = 0; qi < TQ; qi++) accv[qi] += sc[qi][s] * vv;
    }
    for (int qi = 0; qi < TQ; qi++) {
        red[tid] = accv[qi]; __syncthreads();
        if (tid < 64) {
            float r = red[tid] + red[tid + 64] + red[tid + 128] + red[tid + 192];
            o[(size_t)(b * Tt + t0 + qi) * Dd + (h << 6) + tid] = r / sval[qi];
        }
        __syncthreads();
    }
}

__global__ void seg_scan_kernel(const int* __restrict__ tokens, int* __restrict__ segid) {
    int b = blockIdx.x;
    int tid = threadIdx.x;   // 256, each handles 8 consecutive tokens
    const int* trow = tokens + (size_t)b * Tt;
    int base = tid * 8;
    int inc[8];
    int run = 0;
    #pragma unroll
    for (int i = 0; i < 8; i++) {
        int tk = trow[base + i];
        tk = tk < 0 ? 0 : (tk > 255 ? 255 : tk);
        run += is_sep(tk);
        inc[i] = run;
    }
    __shared__ int part[256];
    part[tid] = run;
    __syncthreads();
    for (int off = 1; off < 256; off <<= 1) {
        int vv = (tid >= off) ? part[tid - off] : 0;
        __syncthreads();
        part[tid] += vv;
        __syncthreads();
    }
    int exc = part[tid] - run;
    #pragma unroll
    for (int i = 0; i < 8; i++)
        segid[(size_t)b * Tt + base + i] = exc + inc[i] + b * (Tt + 1);
}

__global__ void seg_cnt_kernel(const int* __restrict__ segid, float* __restrict__ cnt) {
    int i = blockIdx.x * blockDim.x + threadIdx.x;
    if (i < BT) atomicAdd(&cnt[segid[i]], 1.0f);
}

__global__ void seg_accum_kernel(const float* __restrict__ h, const int* __restrict__ segid,
                                 float* __restrict__ segsum) {
    size_t idx = (size_t)blockIdx.x * blockDim.x + threadIdx.x;
    if (idx >= BTD) return;
    size_t row = idx >> 9;
    int d = idx & 511;
    atomicAdd(&segsum[(size_t)segid[row] * Dd + d], h[idx]);
}

__global__ void seg_final_kernel(const float* __restrict__ h, const float* __restrict__ segsum,
                                 const float* __restrict__ cnt, const int* __restrict__ segid,
                                 float* __restrict__ out) {
    size_t idx = (size_t)blockIdx.x * blockDim.x + threadIdx.x;
    if (idx >= BTD) return;
    size_t row = idx >> 9;
    int d = idx & 511;
    int s = segid[row];
    float mean = segsum[(size_t)s * Dd + d] / fmaxf(cnt[s], 1.0f);
    out[idx] = 0.5f * h[idx] + 0.5f * mean;
}

extern "C" void kernel_launch(void* const* d_in, const int* in_sizes, int n_in,
                              void* d_out, int out_size, void* d_ws, size_t ws_size,
                              hipStream_t stream) {
    const int*   tokens       = (const int*)d_in[0];
    const float* embedw       = (const float*)d_in[1];
    const float* attn_norm_w  = (const float*)d_in[2];
    const float* wq           = (const float*)d_in[3];
    const float* wk           = (const float*)d_in[4];
    const float* wv           = (const float*)d_in[5];
    const float* wo           = (const float*)d_in[6];
    const float* ffn_norm_w   = (const float*)d_in[7];
    const float* w1           = (const float*)d_in[8];
    const float* w2           = (const float*)d_in[9];
    const float* w3           = (const float*)d_in[10];
    const float* final_norm_w = (const float*)d_in[11];
    float* out = (float*)d_out;
    float* ws  = (float*)d_ws;

    float* x    = ws;                       // BTD
    float* xn   = ws + BTD;                 // BTD
    float* big  = ws + 2 * BTD;             // 4*BTD region (q,k,v,o during attn; g during FFN; segsum at end)
    float* qb   = big;
    float* kb   = big + BTD;
    float* vb   = big + 2 * BTD;
    float* ob   = big + 3 * BTD;
    float* g    = big;
    float* cosb = ws + 6 * BTD;             // Tt*32
    float* sinb = cosb + (size_t)Tt * 32;   // Tt*32
    float* segsum = big;                    // Bq*(Tt+1)*Dd  (fits in 4*BTD)
    float* segcnt = sinb + (size_t)Tt * 32; // Bq*(Tt+1)
    int*   segid  = (int*)(segcnt + Bq * (Tt + 1)); // BT ints

    embed_kernel<<<(int)((BTD / 4 + 255) / 256), 256, 0, stream>>>(tokens, embedw, x);
    rope_table_kernel<<<(Tt * 32 + 255) / 256, 256, 0, stream>>>(cosb, sinb);

    dim3 g1(Dd / 64, BT / 64);      // 8 x 128
    dim3 g2(HIDN / 64, BT / 64);    // 32 x 128
    dim3 ga(Tt / TQ, Bq * Hh);      // 512 x 32
    int nrope = BT * Hh * 32;

    for (int l = 0; l < Ll; l++) {
        rmsnorm_kernel<<<BT, 256, 0, stream>>>(x, attn_norm_w + (size_t)l * Dd, xn);
        gemm_nt_kernel<false><<<g1, 256, 0, stream>>>(xn, wq + (size_t)l * Dd * Dd, nullptr, qb, BT, Dd, Dd);
        gemm_nt_kernel<false><<<g1, 256, 0, stream>>>(xn, wk + (size_t)l * Dd * Dd, nullptr, kb, BT, Dd, Dd);
        gemm_nt_kernel<false><<<g1, 256, 0, stream>>>(xn, wv + (size_t)l * Dd * Dd, nullptr, vb, BT, Dd, Dd);
        rope_kernel<<<(nrope + 255) / 256, 256, 0, stream>>>(qb, cosb, sinb);
        rope_kernel<<<(nrope + 255) / 256, 256, 0, stream>>>(kb, cosb, sinb);
        attn_kernel<<<ga, 256, 0, stream>>>(qb, kb, vb, ob);
        gemm_nt_kernel<true><<<g1, 256, 0, stream>>>(ob, wo + (size_t)l * Dd * Dd, x, x, BT, Dd, Dd);
        rmsnorm_kernel<<<BT, 256, 0, stream>>>(x, ffn_norm_w + (size_t)l * Dd, xn);
        gemm_swiglu_kernel<<<g2, 256, 0, stream>>>(xn, w1 + (size_t)l * HIDN * Dd,
                                                   w3 + (size_t)l * HIDN * Dd, g, BT, HIDN, Dd);
        gemm_nt_kernel<true><<<g1, 256, 0, stream>>>(g, w2 + (size_t)l * Dd * HIDN, x, x, BT, Dd, HIDN);
    }

    rmsnorm_kernel<<<BT, 256, 0, stream>>>(x, final_norm_w, xn);

    hipMemsetAsync(segsum, 0, (size_t)Bq * (Tt + 1) * Dd * sizeof(float), stream);
    hipMemsetAsync(segcnt, 0, (size_t)Bq * (Tt + 1) * sizeof(float), stream);
    seg_scan_kernel<<<Bq, 256, 0, stream>>>(tokens, segid);
    seg_cnt_kernel<<<(BT + 255) / 256, 256, 0, stream>>>(segid, segcnt);
    seg_accum_kernel<<<(int)((BTD + 255) / 256), 256, 0, stream>>>(xn, segid, segsum);
    seg_final_kernel<<<(int)((BTD + 255) / 256), 256, 0, stream>>>(xn, segsum, segcnt, segid, out);
}

// Round 2
// 4514.343 us; speedup vs baseline: 3.1674x; 3.1674x over previous
//
#include <hip/hip_runtime.h>
#include <math.h>

#define Bq 4
#define Tt 2048
#define Dd 512
#define Hh 8
#define Ll 4
#define HIDN 2048
#define DHd 64
#define BT (Bq*Tt)                 // 8192
#define BTD ((size_t)BT*Dd)        // 4194304

typedef __attribute__((ext_vector_type(8))) __bf16 bf16x8;
typedef __attribute__((ext_vector_type(4))) __bf16 bf16x4;
typedef __attribute__((ext_vector_type(4))) float f32x4;

static __device__ __forceinline__ int is_sep(int t) {
    const unsigned long long w0 = 0xFC00FFFF00002600ULL;
    const unsigned long long w1 = 0x7800000078000001ULL;
    if (t < 64)  return (int)((w0 >> t) & 1ULL);
    if (t < 128) return (int)((w1 >> (t - 64)) & 1ULL);
    return 0;
}

__global__ void embed_kernel(const int* __restrict__ tokens, const float* __restrict__ embed,
                             float* __restrict__ x) {
    size_t idx = (size_t)blockIdx.x * blockDim.x + threadIdx.x;   // over BTD/4 float4
    if (idx >= BTD / 4) return;
    size_t row = idx >> 7;                                        // / (Dd/4)
    int tk = tokens[row];
    tk = tk < 0 ? 0 : (tk > 255 ? 255 : tk);
    const float4* src = (const float4*)(embed + (size_t)tk * Dd);
    ((float4*)x)[idx] = src[idx & 127];
}

__global__ void rope_table_kernel(float* __restrict__ cosb, float* __restrict__ sinb) {
    int idx = blockIdx.x * blockDim.x + threadIdx.x;
    if (idx >= Tt * 32) return;
    int t = idx >> 5, j = idx & 31;
    float inv = powf(10000.0f, -(2.0f * j) / 64.0f);
    float ang = (float)t * inv;
    cosb[idx] = cosf(ang);
    sinb[idx] = sinf(ang);
}

__global__ void rmsnorm_kernel(const float* __restrict__ x, const float* __restrict__ w,
                               float* __restrict__ y) {
    int row = blockIdx.x;
    int tid = threadIdx.x;   // 256
    const float2* xr = (const float2*)(x + (size_t)row * Dd);
    float2 v = xr[tid];
    __shared__ float red[256];
    red[tid] = v.x * v.x + v.y * v.y;
    __syncthreads();
    for (int off = 128; off > 0; off >>= 1) {
        if (tid < off) red[tid] += red[tid + off];
        __syncthreads();
    }
    float scale = rsqrtf(red[0] * (1.0f / Dd) + 1e-6f);
    float2 wv = ((const float2*)w)[tid];
    ((float2*)(y + (size_t)row * Dd))[tid] = make_float2(v.x * scale * wv.x, v.y * scale * wv.y);
}

// C[i,j] = (ADD ? res[i,j] : 0) + sum_k A[i,k]*Bm[j,k]   (both row-major, NT)
template<bool ADD>
__global__ __launch_bounds__(256) void gemm_nt_kernel(
    const float* __restrict__ A, const float* __restrict__ Bm,
    const float* __restrict__ res, float* __restrict__ C,
    int M, int N, int K) {
    __shared__ float As[16][68];
    __shared__ float Bs[16][68];
    int tid = threadIdx.x;
    int tx = tid & 15, ty = tid >> 4;
    int bm = blockIdx.y * 64, bn = blockIdx.x * 64;
    int lrow = tid >> 2;              // 0..63
    int lcol = (tid & 3) << 2;        // 0,4,8,12
    float acc[4][4] = {{0.f}};
    const float* Ab = A + (size_t)(bm + lrow) * K + lcol;
    const float* Bb = Bm + (size_t)(bn + lrow) * K + lcol;
    for (int k0 = 0; k0 < K; k0 += 16) {
        float4 a4 = *(const float4*)(Ab + k0);
        float4 b4 = *(const float4*)(Bb + k0);
        As[lcol + 0][lrow] = a4.x; As[lcol + 1][lrow] = a4.y;
        As[lcol + 2][lrow] = a4.z; As[lcol + 3][lrow] = a4.w;
        Bs[lcol + 0][lrow] = b4.x; Bs[lcol + 1][lrow] = b4.y;
        Bs[lcol + 2][lrow] = b4.z; Bs[lcol + 3][lrow] = b4.w;
        __syncthreads();
        #pragma unroll
        for (int k = 0; k < 16; k++) {
            float av[4], bv[4];
            #pragma unroll
            for (int i = 0; i < 4; i++) av[i] = As[k][(ty << 2) + i];
            #pragma unroll
            for (int j = 0; j < 4; j++) bv[j] = Bs[k][(tx << 2) + j];
            #pragma unroll
            for (int i = 0; i < 4; i++)
                #pragma unroll
                for (int j = 0; j < 4; j++) acc[i][j] = fmaf(av[i], bv[j], acc[i][j]);
        }
        __syncthreads();
    }
    #pragma unroll
    for (int i = 0; i < 4; i++) {
        int r = bm + (ty << 2) + i;
        float4 outv = make_float4(acc[i][0], acc[i][1], acc[i][2], acc[i][3]);
        if (ADD) {
            float4 rv = *(const float4*)(res + (size_t)r * N + bn + (tx << 2));
            outv.x += rv.x; outv.y += rv.y; outv.z += rv.z; outv.w += rv.w;
        }
        *(float4*)(C + (size_t)r * N + bn + (tx << 2)) = outv;
    }
}

// G[i,j] = silu(A@W1^T) * (A@W3^T)
__global__ __launch_bounds__(256) void gemm_swiglu_kernel(
    const float* __restrict__ A, const float* __restrict__ W1,
    const float* __restrict__ W3, float* __restrict__ G,
    int M, int N, int K) {
    __shared__ float As[16][68];
    __shared__ float B1s[16][68];
    __shared__ float B3s[16][68];
    int tid = threadIdx.x;
    int tx = tid & 15, ty = tid >> 4;
    int bm = blockIdx.y * 64, bn = blockIdx.x * 64;
    int lrow = tid >> 2;
    int lcol = (tid & 3) << 2;
    float acc1[4][4] = {{0.f}};
    float acc3[4][4] = {{0.f}};
    const float* Ab = A + (size_t)(bm + lrow) * K + lcol;
    const float* B1b = W1 + (size_t)(bn + lrow) * K + lcol;
    const float* B3b = W3 + (size_t)(bn + lrow) * K + lcol;
    for (int k0 = 0; k0 < K; k0 += 16) {
        float4 a4 = *(const float4*)(Ab + k0);
        float4 b1 = *(const float4*)(B1b + k0);
        float4 b3 = *(const float4*)(B3b + k0);
        As[lcol + 0][lrow] = a4.x; As[lcol + 1][lrow] = a4.y;
        As[lcol + 2][lrow] = a4.z; As[lcol + 3][lrow] = a4.w;
        B1s[lcol + 0][lrow] = b1.x; B1s[lcol + 1][lrow] = b1.y;
        B1s[lcol + 2][lrow] = b1.z; B1s[lcol + 3][lrow] = b1.w;
        B3s[lcol + 0][lrow] = b3.x; B3s[lcol + 1][lrow] = b3.y;
        B3s[lcol + 2][lrow] = b3.z; B3s[lcol + 3][lrow] = b3.w;
        __syncthreads();
        #pragma unroll
        for (int k = 0; k < 16; k++) {
            float av[4], b1v[4], b3v[4];
            #pragma unroll
            for (int i = 0; i < 4; i++) av[i] = As[k][(ty << 2) + i];
            #pragma unroll
            for (int j = 0; j < 4; j++) { b1v[j] = B1s[k][(tx << 2) + j]; b3v[j] = B3s[k][(tx << 2) + j]; }
            #pragma unroll
            for (int i = 0; i < 4; i++)
                #pragma unroll
                for (int j = 0; j < 4; j++) {
                    acc1[i][j] = fmaf(av[i], b1v[j], acc1[i][j]);
                    acc3[i][j] = fmaf(av[i], b3v[j], acc3[i][j]);
                }
        }
        __syncthreads();
    }
    #pragma unroll
    for (int i = 0; i < 4; i++) {
        int r = bm + (ty << 2) + i;
        float4 outv;
        float* po = (float*)&outv;
        #pragma unroll
        for (int j = 0; j < 4; j++) {
            float a1 = acc1[i][j];
            float sig = 1.0f / (1.0f + expf(-a1));
            po[j] = a1 * sig * acc3[i][j];
        }
        *(float4*)(G + (size_t)r * N + bn + (tx << 2)) = outv;
    }
}

__global__ void rope_kernel(float* __restrict__ x, const float* __restrict__ cosb,
                            const float* __restrict__ sinb) {
    int idx = blockIdx.x * blockDim.x + threadIdx.x;   // BT*H*32
    if (idx >= BT * Hh * 32) return;
    int row = idx >> 8;
    int rem = idx & 255;
    int h = rem >> 5, j = rem & 31;
    int t = row & (Tt - 1);
    float c = cosb[(t << 5) + j], s = sinb[(t << 5) + j];
    float2* p = (float2*)(x + (size_t)row * Dd + (h << 6) + (j << 1));
    float2 v = *p;
    *p = make_float2(v.x * c - v.y * s, v.x * s + v.y * c);
}

// Flash-style MFMA attention: block = 4 waves, each wave owns 16 q-rows.
// Grid: (Tt/64, Bq*Hh). KV tiles of 64 staged to LDS as bf16.
__global__ __launch_bounds__(256) void attn_mfma_kernel(
    const float* __restrict__ q, const float* __restrict__ k,
    const float* __restrict__ v, float* __restrict__ o) {
    __shared__ __bf16 Ks[64][72];      // stride 72: b128 frag reads ~2-way aliased (free)
    __shared__ __bf16 Vs[64][66];      // stride 66: u16 frag reads conflict-free
    __shared__ __bf16 Ps[4][16][72];   // per-wave P tile

    int tid = threadIdx.x;
    int w = tid >> 6;            // wave 0..3
    int lane = tid & 63;
    int l15 = lane & 15;
    int g = lane >> 4;           // 0..3
    int bh = blockIdx.y;
    int b = bh >> 3, h = bh & 7;
    int qbase = blockIdx.x * 64;

    const float* qp = q + (size_t)b * Tt * Dd + (size_t)h * DHd;
    const float* kp = k + (size_t)b * Tt * Dd + (size_t)h * DHd;
    const float* vp = v + (size_t)b * Tt * Dd + (size_t)h * DHd;

    // Q fragments (pre-scaled by 1/8, exact in bf16): A-frag lane l = row l&15, d = dc*32 + (l>>4)*8 + j
    bf16x8 qa[2];
    {
        const float* qrow = qp + (size_t)(qbase + w * 16 + l15) * Dd;
        #pragma unroll
        for (int dc = 0; dc < 2; dc++) {
            float4 a = *(const float4*)(qrow + dc * 32 + g * 8);
            float4 b2 = *(const float4*)(qrow + dc * 32 + g * 8 + 4);
            qa[dc][0] = (__bf16)(a.x * 0.125f);  qa[dc][1] = (__bf16)(a.y * 0.125f);
            qa[dc][2] = (__bf16)(a.z * 0.125f);  qa[dc][3] = (__bf16)(a.w * 0.125f);
            qa[dc][4] = (__bf16)(b2.x * 0.125f); qa[dc][5] = (__bf16)(b2.y * 0.125f);
            qa[dc][6] = (__bf16)(b2.z * 0.125f); qa[dc][7] = (__bf16)(b2.w * 0.125f);
        }
    }

    f32x4 oacc[4];
    #pragma unroll
    for (int i = 0; i < 4; i++) oacc[i] = (f32x4){0.f, 0.f, 0.f, 0.f};
    float mrun[4] = {-1e30f, -1e30f, -1e30f, -1e30f};
    float lrun[4] = {0.f, 0.f, 0.f, 0.f};

    for (int t = 0; t < Tt / 64; t++) {
        int kv0 = t * 64;
        __syncthreads();   // protect Ks/Vs against overwrite while still being read
        // stage K,V tile (64x64 fp32 -> bf16), 4 float4 per thread per tensor
        #pragma unroll
        for (int p = 0; p < 4; p++) {
            int f = p * 256 + tid;
            int row = f >> 4, c4 = (f & 15) * 4;
            float4 kf = *(const float4*)(kp + (size_t)(kv0 + row) * Dd + c4);
            float4 vf = *(const float4*)(vp + (size_t)(kv0 + row) * Dd + c4);
            bf16x4 kh, vh;
            kh[0] = (__bf16)kf.x; kh[1] = (__bf16)kf.y; kh[2] = (__bf16)kf.z; kh[3] = (__bf16)kf.w;
            vh[0] = (__bf16)vf.x; vh[1] = (__bf16)vf.y; vh[2] = (__bf16)vf.z; vh[3] = (__bf16)vf.w;
            *(bf16x4*)&Ks[row][c4] = kh;
            *(bf16x4*)&Vs[row][c4] = vh;
        }
        __syncthreads();

        // QK^T: S[qrow][kvrow] for 16x64, 4 col-tiles x 2 d-chunks
        f32x4 s[4];
        #pragma unroll
        for (int c = 0; c < 4; c++) {
            s[c] = (f32x4){0.f, 0.f, 0.f, 0.f};
            bf16x8 kb0 = *(const bf16x8*)&Ks[c * 16 + l15][g * 8];
            s[c] = __builtin_amdgcn_mfma_f32_16x16x32_bf16(qa[0], kb0, s[c], 0, 0, 0);
            bf16x8 kb1 = *(const bf16x8*)&Ks[c * 16 + l15][32 + g * 8];
            s[c] = __builtin_amdgcn_mfma_f32_16x16x32_bf16(qa[1], kb1, s[c], 0, 0, 0);
        }

        // online softmax. C layout: row=(lane>>4)*4+r, col=c*16+(lane&15)
        float tmax[4], alpha[4], psum[4];
        #pragma unroll
        for (int r = 0; r < 4; r++) {
            tmax[r] = fmaxf(fmaxf(s[0][r], s[1][r]), fmaxf(s[2][r], s[3][r]));
            #pragma unroll
            for (int off = 1; off < 16; off <<= 1)
                tmax[r] = fmaxf(tmax[r], __shfl_xor(tmax[r], off));
            float mnew = fmaxf(mrun[r], tmax[r]);
            alpha[r] = __expf(mrun[r] - mnew);
            mrun[r] = mnew;
            psum[r] = 0.f;
        }
        float pv[4][4];
        #pragma unroll
        for (int c = 0; c < 4; c++)
            #pragma unroll
            for (int r = 0; r < 4; r++) {
                pv[c][r] = __expf(s[c][r] - mrun[r]);
                psum[r] += pv[c][r];
            }
        #pragma unroll
        for (int r = 0; r < 4; r++) {
            #pragma unroll
            for (int off = 1; off < 16; off <<= 1)
                psum[r] += __shfl_xor(psum[r], off);
            lrun[r] = lrun[r] * alpha[r] + psum[r];
        }
        // rescale O
        #pragma unroll
        for (int d2 = 0; d2 < 4; d2++)
            #pragma unroll
            for (int r = 0; r < 4; r++) oacc[d2][r] *= alpha[r];
        // write P (bf16) to per-wave LDS tile
        #pragma unroll
        for (int c = 0; c < 4; c++)
            #pragma unroll
            for (int r = 0; r < 4; r++)
                Ps[w][g * 4 + r][c * 16 + l15] = (__bf16)pv[c][r];
        __syncthreads();

        // PV: A-frag from Ps, B-frag from Vs (scalar u16 reads, conflict-free)
        bf16x8 pa0 = *(const bf16x8*)&Ps[w][l15][g * 8];
        bf16x8 pa1 = *(const bf16x8*)&Ps[w][l15][32 + g * 8];
        #pragma unroll
        for (int d2 = 0; d2 < 4; d2++) {
            bf16x8 vb0, vb1;
            #pragma unroll
            for (int i = 0; i < 8; i++) {
                vb0[i] = Vs[g * 8 + i][d2 * 16 + l15];
                vb1[i] = Vs[32 + g * 8 + i][d2 * 16 + l15];
            }
            oacc[d2] = __builtin_amdgcn_mfma_f32_16x16x32_bf16(pa0, vb0, oacc[d2], 0, 0, 0);
            oacc[d2] = __builtin_amdgcn_mfma_f32_16x16x32_bf16(pa1, vb1, oacc[d2], 0, 0, 0);
        }
    }

    // epilogue
    float* op = o + (size_t)b * Tt * Dd + (size_t)h * DHd;
    #pragma unroll
    for (int d2 = 0; d2 < 4; d2++)
        #pragma unroll
        for (int r = 0; r < 4; r++)
            op[(size_t)(qbase + w * 16 + g * 4 + r) * Dd + d2 * 16 + l15] = oacc[d2][r] / lrun[r];
}

__global__ void seg_scan_kernel(const int* __restrict__ tokens, int* __restrict__ segid) {
    int b = blockIdx.x;
    int tid = threadIdx.x;   // 256, each handles 8 consecutive tokens
    const int* trow = tokens + (size_t)b * Tt;
    int base = tid * 8;
    int inc[8];
    int run = 0;
    #pragma unroll
    for (int i = 0; i < 8; i++) {
        int tk = trow[base + i];
        tk = tk < 0 ? 0 : (tk > 255 ? 255 : tk);
        run += is_sep(tk);
        inc[i] = run;
    }
    __shared__ int part[256];
    part[tid] = run;
    __syncthreads();
    for (int off = 1; off < 256; off <<= 1) {
        int vv = (tid >= off) ? part[tid - off] : 0;
        __syncthreads();
        part[tid] += vv;
        __syncthreads();
    }
    int exc = part[tid] - run;
    #pragma unroll
    for (int i = 0; i < 8; i++)
        segid[(size_t)b * Tt + base + i] = exc + inc[i] + b * (Tt + 1);
}

__global__ void seg_cnt_kernel(const int* __restrict__ segid, float* __restrict__ cnt) {
    int i = blockIdx.x * blockDim.x + threadIdx.x;
    if (i < BT) atomicAdd(&cnt[segid[i]], 1.0f);
}

__global__ void seg_accum_kernel(const float* __restrict__ h, const int* __restrict__ segid,
                                 float* __restrict__ segsum) {
    size_t idx = (size_t)blockIdx.x * blockDim.x + threadIdx.x;
    if (idx >= BTD) return;
    size_t row = idx >> 9;
    int d = idx & 511;
    atomicAdd(&segsum[(size_t)segid[row] * Dd + d], h[idx]);
}

__global__ void seg_final_kernel(const float* __restrict__ h, const float* __restrict__ segsum,
                                 const float* __restrict__ cnt, const int* __restrict__ segid,
                                 float* __restrict__ out) {
    size_t idx = (size_t)blockIdx.x * blockDim.x + threadIdx.x;
    if (idx >= BTD) return;
    size_t row = idx >> 9;
    int d = idx & 511;
    int s = segid[row];
    float mean = segsum[(size_t)s * Dd + d] / fmaxf(cnt[s], 1.0f);
    out[idx] = 0.5f * h[idx] + 0.5f * mean;
}

extern "C" void kernel_launch(void* const* d_in, const int* in_sizes, int n_in,
                              void* d_out, int out_size, void* d_ws, size_t ws_size,
                              hipStream_t stream) {
    const int*   tokens       = (const int*)d_in[0];
    const float* embedw       = (const float*)d_in[1];
    const float* attn_norm_w  = (const float*)d_in[2];
    const float* wq           = (const float*)d_in[3];
    const float* wk           = (const float*)d_in[4];
    const float* wv           = (const float*)d_in[5];
    const float* wo           = (const float*)d_in[6];
    const float* ffn_norm_w   = (const float*)d_in[7];
    const float* w1           = (const float*)d_in[8];
    const float* w2           = (const float*)d_in[9];
    const float* w3           = (const float*)d_in[10];
    const float* final_norm_w = (const float*)d_in[11];
    float* out = (float*)d_out;
    float* ws  = (float*)d_ws;

    float* x    = ws;                       // BTD
    float* xn   = ws + BTD;                 // BTD
    float* big  = ws + 2 * BTD;             // 4*BTD region
    float* qb   = big;
    float* kb   = big + BTD;
    float* vb   = big + 2 * BTD;
    float* ob   = big + 3 * BTD;
    float* g    = big;
    float* cosb = ws + 6 * BTD;             // Tt*32
    float* sinb = cosb + (size_t)Tt * 32;   // Tt*32
    float* segsum = big;                    // Bq*(Tt+1)*Dd
    float* segcnt = sinb + (size_t)Tt * 32; // Bq*(Tt+1)
    int*   segid  = (int*)(segcnt + Bq * (Tt + 1)); // BT ints

    embed_kernel<<<(int)((BTD / 4 + 255) / 256), 256, 0, stream>>>(tokens, embedw, x);
    rope_table_kernel<<<(Tt * 32 + 255) / 256, 256, 0, stream>>>(cosb, sinb);

    dim3 g1(Dd / 64, BT / 64);      // 8 x 128
    dim3 g2(HIDN / 64, BT / 64);    // 32 x 128
    dim3 ga(Tt / 64, Bq * Hh);      // 32 x 32
    int nrope = BT * Hh * 32;

    for (int l = 0; l < Ll; l++) {
        rmsnorm_kernel<<<BT, 256, 0, stream>>>(x, attn_norm_w + (size_t)l * Dd, xn);
        gemm_nt_kernel<false><<<g1, 256, 0, stream>>>(xn, wq + (size_t)l * Dd * Dd, nullptr, qb, BT, Dd, Dd);
        gemm_nt_kernel<false><<<g1, 256, 0, stream>>>(xn, wk + (size_t)l * Dd * Dd, nullptr, kb, BT, Dd, Dd);
        gemm_nt_kernel<false><<<g1, 256, 0, stream>>>(xn, wv + (size_t)l * Dd * Dd, nullptr, vb, BT, Dd, Dd);
        rope_kernel<<<(nrope + 255) / 256, 256, 0, stream>>>(qb, cosb, sinb);
        rope_kernel<<<(nrope + 255) / 256, 256, 0, stream>>>(kb, cosb, sinb);
        attn_mfma_kernel<<<ga, 256, 0, stream>>>(qb, kb, vb, ob);
        gemm_nt_kernel<true><<<g1, 256, 0, stream>>>(ob, wo + (size_t)l * Dd * Dd, x, x, BT, Dd, Dd);
        rmsnorm_kernel<<<BT, 256, 0, stream>>>(x, ffn_norm_w + (size_t)l * Dd, xn);
        gemm_swiglu_kernel<<<g2, 256, 0, stream>>>(xn, w1 + (size_t)l * HIDN * Dd,
                                                   w3 + (size_t)l * HIDN * Dd, g, BT, HIDN, Dd);
        gemm_nt_kernel<true><<<g1, 256, 0, stream>>>(g, w2 + (size_t)l * Dd * HIDN, x, x, BT, Dd, HIDN);
    }

    rmsnorm_kernel<<<BT, 256, 0, stream>>>(x, final_norm_w, xn);

    hipMemsetAsync(segsum, 0, (size_t)Bq * (Tt + 1) * Dd * sizeof(float), stream);
    hipMemsetAsync(segcnt, 0, (size_t)Bq * (Tt + 1) * sizeof(float), stream);
    seg_scan_kernel<<<Bq, 256, 0, stream>>>(tokens, segid);
    seg_cnt_kernel<<<(BT + 255) / 256, 256, 0, stream>>>(segid, segcnt);
    seg_accum_kernel<<<(int)((BTD + 255) / 256), 256, 0, stream>>>(xn, segid, segsum);
    seg_final_kernel<<<(int)((BTD + 255) / 256), 256, 0, stream>>>(xn, segsum, segcnt, segid, out);
}

// Round 4
// 1339.521 us; speedup vs baseline: 10.6745x; 3.3701x over previous
//
#include <hip/hip_runtime.h>
#include <math.h>

#define Bq 4
#define Tt 2048
#define Dd 512
#define Hh 8
#define Ll 4
#define HIDN 2048
#define DHd 64
#define BT (Bq*Tt)                 // 8192
#define BTD ((size_t)BT*Dd)        // 4194304

typedef __attribute__((ext_vector_type(8))) __bf16 bf16x8;
typedef __attribute__((ext_vector_type(4))) __bf16 bf16x4;
typedef __attribute__((ext_vector_type(2))) __bf16 bf16x2;
typedef __attribute__((ext_vector_type(4))) float f32x4;

static __device__ __forceinline__ int is_sep(int t) {
    const unsigned long long w0 = 0xFC00FFFF00002600ULL;
    const unsigned long long w1 = 0x7800000078000001ULL;
    if (t < 64)  return (int)((w0 >> t) & 1ULL);
    if (t < 128) return (int)((w1 >> (t - 64)) & 1ULL);
    return 0;
}

static __device__ __forceinline__ void gload16(const void* g, void* l) {
    __builtin_amdgcn_global_load_lds(
        (const __attribute__((address_space(1))) void*)g,
        (__attribute__((address_space(3))) void*)l, 16, 0, 0);
}

__global__ void embed_kernel(const int* __restrict__ tokens, const float* __restrict__ embed,
                             float* __restrict__ x) {
    size_t idx = (size_t)blockIdx.x * blockDim.x + threadIdx.x;
    if (idx >= BTD / 4) return;
    size_t row = idx >> 7;
    int tk = tokens[row];
    tk = tk < 0 ? 0 : (tk > 255 ? 255 : tk);
    const float4* src = (const float4*)(embed + (size_t)tk * Dd);
    ((float4*)x)[idx] = src[idx & 127];
}

__global__ void rope_table_kernel(float* __restrict__ cosb, float* __restrict__ sinb) {
    int idx = blockIdx.x * blockDim.x + threadIdx.x;
    if (idx >= Tt * 32) return;
    int t = idx >> 5, j = idx & 31;
    float inv = powf(10000.0f, -(2.0f * j) / 64.0f);
    float ang = (float)t * inv;
    cosb[idx] = cosf(ang);
    sinb[idx] = sinf(ang);
}

__global__ void cvt_bf16_kernel(const float* __restrict__ in, __bf16* __restrict__ out, int n8) {
    int i = blockIdx.x * blockDim.x + threadIdx.x;
    if (i >= n8) return;
    const float4* p = (const float4*)(in + (size_t)i * 8);
    float4 a = p[0], b = p[1];
    bf16x8 o8;
    o8[0] = (__bf16)a.x; o8[1] = (__bf16)a.y; o8[2] = (__bf16)a.z; o8[3] = (__bf16)a.w;
    o8[4] = (__bf16)b.x; o8[5] = (__bf16)b.y; o8[6] = (__bf16)b.z; o8[7] = (__bf16)b.w;
    *(bf16x8*)(out + (size_t)i * 8) = o8;
}

// fp32 in, fp32 out (final norm)
__global__ void rmsnorm_kernel(const float* __restrict__ x, const float* __restrict__ w,
                               float* __restrict__ y) {
    int row = blockIdx.x;
    int tid = threadIdx.x;
    const float2* xr = (const float2*)(x + (size_t)row * Dd);
    float2 v = xr[tid];
    __shared__ float red[256];
    red[tid] = v.x * v.x + v.y * v.y;
    __syncthreads();
    for (int off = 128; off > 0; off >>= 1) {
        if (tid < off) red[tid] += red[tid + off];
        __syncthreads();
    }
    float scale = rsqrtf(red[0] * (1.0f / Dd) + 1e-6f);
    float2 wv = ((const float2*)w)[tid];
    ((float2*)(y + (size_t)row * Dd))[tid] = make_float2(v.x * scale * wv.x, v.y * scale * wv.y);
}

// fp32 in, bf16 out (layer norms feeding MFMA GEMMs)
__global__ void rmsnorm_bf16_kernel(const float* __restrict__ x, const float* __restrict__ w,
                                    __bf16* __restrict__ y) {
    int row = blockIdx.x;
    int tid = threadIdx.x;
    const float2* xr = (const float2*)(x + (size_t)row * Dd);
    float2 v = xr[tid];
    __shared__ float red[256];
    red[tid] = v.x * v.x + v.y * v.y;
    __syncthreads();
    for (int off = 128; off > 0; off >>= 1) {
        if (tid < off) red[tid] += red[tid + off];
        __syncthreads();
    }
    float scale = rsqrtf(red[0] * (1.0f / Dd) + 1e-6f);
    float2 wv = ((const float2*)w)[tid];
    bf16x2 o;
    o[0] = (__bf16)(v.x * scale * wv.x);
    o[1] = (__bf16)(v.y * scale * wv.y);
    *(bf16x2*)(y + (size_t)row * Dd + 2 * tid) = o;
}

// C = A(bf16) @ Bw(bf16)^T [+ res(f32)]. 128x128 tile, BK=32, 4 waves, double-buffered
// global_load_lds staging. EPI 0: bf16 out, EPI 1: f32 out + f32 residual.
template<int EPI>
__global__ __launch_bounds__(256) void gemm_bt_mfma(
    const __bf16* __restrict__ A, const __bf16* __restrict__ Bw,
    const float* __restrict__ res, void* __restrict__ Cout,
    int N, int K) {
    __shared__ __align__(16) __bf16 lds[2][2][128 * 32];
    const int tid = threadIdx.x;
    const int w = tid >> 6, lane = tid & 63;
    const int l15 = lane & 15, g4 = lane >> 4;
    const int wr = w >> 1, wc = w & 1;
    const int bm = blockIdx.y * 128, bn = blockIdx.x * 128;
    const int lrow = lane >> 2, lc8 = (lane & 3) * 8;
    const int chunk0 = w * 2;

    f32x4 acc[4][4];
    #pragma unroll
    for (int m = 0; m < 4; m++)
        #pragma unroll
        for (int n = 0; n < 4; n++) acc[m][n] = (f32x4){0.f, 0.f, 0.f, 0.f};

    auto stage = [&](int buf, int k0) {
        #pragma unroll
        for (int c = 0; c < 2; c++) {
            int chunk = chunk0 + c;
            const __bf16* ga = A + (size_t)(bm + chunk * 16 + lrow) * K + k0 + lc8;
            gload16(ga, &lds[buf][0][chunk * 512]);
            const __bf16* gb = Bw + (size_t)(bn + chunk * 16 + lrow) * K + k0 + lc8;
            gload16(gb, &lds[buf][1][chunk * 512]);
        }
    };

    stage(0, 0);
    __syncthreads();
    const int NT = K >> 5;
    int cur = 0;
    for (int t = 0; t < NT; t++) {
        if (t + 1 < NT) stage(cur ^ 1, (t + 1) << 5);
        const __bf16* Al = &lds[cur][0][0];
        const __bf16* Bl = &lds[cur][1][0];
        bf16x8 af[4], bfr[4];
        #pragma unroll
        for (int m = 0; m < 4; m++)
            af[m] = *(const bf16x8*)&Al[(wr * 64 + m * 16 + l15) * 32 + g4 * 8];
        #pragma unroll
        for (int n = 0; n < 4; n++)
            bfr[n] = *(const bf16x8*)&Bl[(wc * 64 + n * 16 + l15) * 32 + g4 * 8];
        #pragma unroll
        for (int m = 0; m < 4; m++)
            #pragma unroll
            for (int n = 0; n < 4; n++)
                acc[m][n] = __builtin_amdgcn_mfma_f32_16x16x32_bf16(af[m], bfr[n], acc[m][n], 0, 0, 0);
        __syncthreads();
        cur ^= 1;
    }

    #pragma unroll
    for (int m = 0; m < 4; m++)
        #pragma unroll
        for (int n = 0; n < 4; n++)
            #pragma unroll
            for (int r = 0; r < 4; r++) {
                size_t row = bm + wr * 64 + m * 16 + g4 * 4 + r;
                size_t col = bn + wc * 64 + n * 16 + l15;
                if (EPI == 0) {
                    ((__bf16*)Cout)[row * N + col] = (__bf16)acc[m][n][r];
                } else {
                    ((float*)Cout)[row * N + col] = acc[m][n][r] + res[row * N + col];
                }
            }
}

// G = silu(A@W1^T) * (A@W3^T), bf16 out. Same structure, dual B.
__global__ __launch_bounds__(256) void gemm_swiglu_mfma(
    const __bf16* __restrict__ A, const __bf16* __restrict__ W1,
    const __bf16* __restrict__ W3, __bf16* __restrict__ G,
    int N, int K) {
    __shared__ __align__(16) __bf16 lds[2][3][128 * 32];
    const int tid = threadIdx.x;
    const int w = tid >> 6, lane = tid & 63;
    const int l15 = lane & 15, g4 = lane >> 4;
    const int wr = w >> 1, wc = w & 1;
    const int bm = blockIdx.y * 128, bn = blockIdx.x * 128;
    const int lrow = lane >> 2, lc8 = (lane & 3) * 8;
    const int chunk0 = w * 2;

    f32x4 acc1[4][4], acc3[4][4];
    #pragma unroll
    for (int m = 0; m < 4; m++)
        #pragma unroll
        for (int n = 0; n < 4; n++) {
            acc1[m][n] = (f32x4){0.f, 0.f, 0.f, 0.f};
            acc3[m][n] = (f32x4){0.f, 0.f, 0.f, 0.f};
        }

    auto stage = [&](int buf, int k0) {
        #pragma unroll
        for (int c = 0; c < 2; c++) {
            int chunk = chunk0 + c;
            const __bf16* ga = A + (size_t)(bm + chunk * 16 + lrow) * K + k0 + lc8;
            gload16(ga, &lds[buf][0][chunk * 512]);
            const __bf16* g1 = W1 + (size_t)(bn + chunk * 16 + lrow) * K + k0 + lc8;
            gload16(g1, &lds[buf][1][chunk * 512]);
            const __bf16* g3 = W3 + (size_t)(bn + chunk * 16 + lrow) * K + k0 + lc8;
            gload16(g3, &lds[buf][2][chunk * 512]);
        }
    };

    stage(0, 0);
    __syncthreads();
    const int NT = K >> 5;
    int cur = 0;
    for (int t = 0; t < NT; t++) {
        if (t + 1 < NT) stage(cur ^ 1, (t + 1) << 5);
        const __bf16* Al = &lds[cur][0][0];
        const __bf16* B1 = &lds[cur][1][0];
        const __bf16* B3 = &lds[cur][2][0];
        bf16x8 af[4];
        #pragma unroll
        for (int m = 0; m < 4; m++)
            af[m] = *(const bf16x8*)&Al[(wr * 64 + m * 16 + l15) * 32 + g4 * 8];
        #pragma unroll
        for (int n = 0; n < 4; n++) {
            bf16x8 b1 = *(const bf16x8*)&B1[(wc * 64 + n * 16 + l15) * 32 + g4 * 8];
            bf16x8 b3 = *(const bf16x8*)&B3[(wc * 64 + n * 16 + l15) * 32 + g4 * 8];
            #pragma unroll
            for (int m = 0; m < 4; m++) {
                acc1[m][n] = __builtin_amdgcn_mfma_f32_16x16x32_bf16(af[m], b1, acc1[m][n], 0, 0, 0);
                acc3[m][n] = __builtin_amdgcn_mfma_f32_16x16x32_bf16(af[m], b3, acc3[m][n], 0, 0, 0);
            }
        }
        __syncthreads();
        cur ^= 1;
    }

    #pragma unroll
    for (int m = 0; m < 4; m++)
        #pragma unroll
        for (int n = 0; n < 4; n++)
            #pragma unroll
            for (int r = 0; r < 4; r++) {
                size_t row = bm + wr * 64 + m * 16 + g4 * 4 + r;
                size_t col = bn + wc * 64 + n * 16 + l15;
                float a1 = acc1[m][n][r];
                float sig = 1.0f / (1.0f + __expf(-a1));
                G[row * N + col] = (__bf16)(a1 * sig * acc3[m][n][r]);
            }
}

// RoPE on bf16 [BT][512]; thread handles 8 contiguous elems (4 pairs). SCALE folds 1/8 q-scale.
template<bool SCALE>
__global__ void rope_bf16_kernel(__bf16* __restrict__ x, const float* __restrict__ cosb,
                                 const float* __restrict__ sinb) {
    int idx = blockIdx.x * blockDim.x + threadIdx.x;   // BT*64
    if (idx >= BT * 64) return;
    int row = idx >> 6, seg = idx & 63;
    int t = row & (Tt - 1);
    int j4 = (seg & 7) * 4;                            // pair base within head
    bf16x8 v = *(bf16x8*)(x + (size_t)row * Dd + seg * 8);
    float4 c4 = *(const float4*)(cosb + (t << 5) + j4);
    float4 s4 = *(const float4*)(sinb + (t << 5) + j4);
    const float* cp = (const float*)&c4;
    const float* sp = (const float*)&s4;
    bf16x8 o;
    #pragma unroll
    for (int p = 0; p < 4; p++) {
        float a = (float)v[2 * p], b = (float)v[2 * p + 1];
        float r1 = a * cp[p] - b * sp[p];
        float r2 = a * sp[p] + b * cp[p];
        if (SCALE) { r1 *= 0.125f; r2 *= 0.125f; }
        o[2 * p] = (__bf16)r1;
        o[2 * p + 1] = (__bf16)r2;
    }
    *(bf16x8*)(x + (size_t)row * Dd + seg * 8) = o;
}

// Flash-style MFMA attention, bf16 q/k/v in, bf16 o out. q pre-scaled by 1/8.
__global__ __launch_bounds__(256) void attn_mfma_kernel(
    const __bf16* __restrict__ q, const __bf16* __restrict__ k,
    const __bf16* __restrict__ v, __bf16* __restrict__ o) {
    __shared__ __align__(16) __bf16 Ks[64][72];
    __shared__ __align__(16) __bf16 Vs[64][66];
    __shared__ __align__(16) __bf16 Ps[4][16][72];

    int tid = threadIdx.x;
    int w = tid >> 6;
    int lane = tid & 63;
    int l15 = lane & 15;
    int g = lane >> 4;
    int bh = blockIdx.y;
    int b = bh >> 3, h = bh & 7;
    int qbase = blockIdx.x * 64;

    const __bf16* qp = q + (size_t)b * Tt * Dd + (size_t)h * DHd;
    const __bf16* kp = k + (size_t)b * Tt * Dd + (size_t)h * DHd;
    const __bf16* vp = v + (size_t)b * Tt * Dd + (size_t)h * DHd;

    bf16x8 qa[2];
    {
        const __bf16* qrow = qp + (size_t)(qbase + w * 16 + l15) * Dd;
        qa[0] = *(const bf16x8*)(qrow + g * 8);
        qa[1] = *(const bf16x8*)(qrow + 32 + g * 8);
    }

    f32x4 oacc[4];
    #pragma unroll
    for (int i = 0; i < 4; i++) oacc[i] = (f32x4){0.f, 0.f, 0.f, 0.f};
    float mrun[4] = {-1e30f, -1e30f, -1e30f, -1e30f};
    float lrun[4] = {0.f, 0.f, 0.f, 0.f};

    for (int t = 0; t < Tt / 64; t++) {
        int kv0 = t * 64;
        __syncthreads();
        #pragma unroll
        for (int p = 0; p < 2; p++) {
            int f = p * 256 + tid;          // 0..511
            int row = f >> 3, c8 = (f & 7) * 8;
            bf16x8 kv = *(const bf16x8*)(kp + (size_t)(kv0 + row) * Dd + c8);
            *(bf16x8*)&Ks[row][c8] = kv;
            bf16x8 vv = *(const bf16x8*)(vp + (size_t)(kv0 + row) * Dd + c8);
            #pragma unroll
            for (int j = 0; j < 8; j++) Vs[row][c8 + j] = vv[j];
        }
        __syncthreads();

        f32x4 s[4];
        #pragma unroll
        for (int c = 0; c < 4; c++) {
            s[c] = (f32x4){0.f, 0.f, 0.f, 0.f};
            bf16x8 kb0 = *(const bf16x8*)&Ks[c * 16 + l15][g * 8];
            s[c] = __builtin_amdgcn_mfma_f32_16x16x32_bf16(qa[0], kb0, s[c], 0, 0, 0);
            bf16x8 kb1 = *(const bf16x8*)&Ks[c * 16 + l15][32 + g * 8];
            s[c] = __builtin_amdgcn_mfma_f32_16x16x32_bf16(qa[1], kb1, s[c], 0, 0, 0);
        }

        float tmax[4], alpha[4], psum[4];
        #pragma unroll
        for (int r = 0; r < 4; r++) {
            tmax[r] = fmaxf(fmaxf(s[0][r], s[1][r]), fmaxf(s[2][r], s[3][r]));
            #pragma unroll
            for (int off = 1; off < 16; off <<= 1)
                tmax[r] = fmaxf(tmax[r], __shfl_xor(tmax[r], off));
            float mnew = fmaxf(mrun[r], tmax[r]);
            alpha[r] = __expf(mrun[r] - mnew);
            mrun[r] = mnew;
            psum[r] = 0.f;
        }
        float pv[4][4];
        #pragma unroll
        for (int c = 0; c < 4; c++)
            #pragma unroll
            for (int r = 0; r < 4; r++) {
                pv[c][r] = __expf(s[c][r] - mrun[r]);
                psum[r] += pv[c][r];
            }
        #pragma unroll
        for (int r = 0; r < 4; r++) {
            #pragma unroll
            for (int off = 1; off < 16; off <<= 1)
                psum[r] += __shfl_xor(psum[r], off);
            lrun[r] = lrun[r] * alpha[r] + psum[r];
        }
        #pragma unroll
        for (int d2 = 0; d2 < 4; d2++)
            #pragma unroll
            for (int r = 0; r < 4; r++) oacc[d2][r] *= alpha[r];
        #pragma unroll
        for (int c = 0; c < 4; c++)
            #pragma unroll
            for (int r = 0; r < 4; r++)
                Ps[w][g * 4 + r][c * 16 + l15] = (__bf16)pv[c][r];
        __syncthreads();

        bf16x8 pa0 = *(const bf16x8*)&Ps[w][l15][g * 8];
        bf16x8 pa1 = *(const bf16x8*)&Ps[w][l15][32 + g * 8];
        #pragma unroll
        for (int d2 = 0; d2 < 4; d2++) {
            bf16x8 vb0, vb1;
            #pragma unroll
            for (int i = 0; i < 8; i++) {
                vb0[i] = Vs[g * 8 + i][d2 * 16 + l15];
                vb1[i] = Vs[32 + g * 8 + i][d2 * 16 + l15];
            }
            oacc[d2] = __builtin_amdgcn_mfma_f32_16x16x32_bf16(pa0, vb0, oacc[d2], 0, 0, 0);
            oacc[d2] = __builtin_amdgcn_mfma_f32_16x16x32_bf16(pa1, vb1, oacc[d2], 0, 0, 0);
        }
    }

    __bf16* op = o + (size_t)b * Tt * Dd + (size_t)h * DHd;
    #pragma unroll
    for (int d2 = 0; d2 < 4; d2++)
        #pragma unroll
        for (int r = 0; r < 4; r++)
            op[(size_t)(qbase + w * 16 + g * 4 + r) * Dd + d2 * 16 + l15] =
                (__bf16)(oacc[d2][r] / lrun[r]);
}

__global__ void seg_scan_kernel(const int* __restrict__ tokens, int* __restrict__ segid) {
    int b = blockIdx.x;
    int tid = threadIdx.x;
    const int* trow = tokens + (size_t)b * Tt;
    int base = tid * 8;
    int inc[8];
    int run = 0;
    #pragma unroll
    for (int i = 0; i < 8; i++) {
        int tk = trow[base + i];
        tk = tk < 0 ? 0 : (tk > 255 ? 255 : tk);
        run += is_sep(tk);
        inc[i] = run;
    }
    __shared__ int part[256];
    part[tid] = run;
    __syncthreads();
    for (int off = 1; off < 256; off <<= 1) {
        int vv = (tid >= off) ? part[tid - off] : 0;
        __syncthreads();
        part[tid] += vv;
        __syncthreads();
    }
    int exc = part[tid] - run;
    #pragma unroll
    for (int i = 0; i < 8; i++)
        segid[(size_t)b * Tt + base + i] = exc + inc[i] + b * (Tt + 1);
}

__global__ void seg_cnt_kernel(const int* __restrict__ segid, float* __restrict__ cnt) {
    int i = blockIdx.x * blockDim.x + threadIdx.x;
    if (i < BT) atomicAdd(&cnt[segid[i]], 1.0f);
}

__global__ void seg_accum_kernel(const float* __restrict__ h, const int* __restrict__ segid,
                                 float* __restrict__ segsum) {
    size_t idx = (size_t)blockIdx.x * blockDim.x + threadIdx.x;
    if (idx >= BTD) return;
    size_t row = idx >> 9;
    int d = idx & 511;
    atomicAdd(&segsum[(size_t)segid[row] * Dd + d], h[idx]);
}

__global__ void seg_final_kernel(const float* __restrict__ h, const float* __restrict__ segsum,
                                 const float* __restrict__ cnt, const int* __restrict__ segid,
                                 float* __restrict__ out) {
    size_t idx = (size_t)blockIdx.x * blockDim.x + threadIdx.x;
    if (idx >= BTD) return;
    size_t row = idx >> 9;
    int d = idx & 511;
    int s = segid[row];
    float mean = segsum[(size_t)s * Dd + d] / fmaxf(cnt[s], 1.0f);
    out[idx] = 0.5f * h[idx] + 0.5f * mean;
}

extern "C" void kernel_launch(void* const* d_in, const int* in_sizes, int n_in,
                              void* d_out, int out_size, void* d_ws, size_t ws_size,
                              hipStream_t stream) {
    const int*   tokens       = (const int*)d_in[0];
    const float* embedw       = (const float*)d_in[1];
    const float* attn_norm_w  = (const float*)d_in[2];
    const float* wq           = (const float*)d_in[3];
    const float* wk           = (const float*)d_in[4];
    const float* wv           = (const float*)d_in[5];
    const float* wo           = (const float*)d_in[6];
    const float* ffn_norm_w   = (const float*)d_in[7];
    const float* w1           = (const float*)d_in[8];
    const float* w2           = (const float*)d_in[9];
    const float* w3           = (const float*)d_in[10];
    const float* final_norm_w = (const float*)d_in[11];
    float* out = (float*)d_out;
    float* ws  = (float*)d_ws;

    // layout (floats): x | qkvo(2*BTD f = 4*BTD bf16) | xn_bf(BTD/2) | wbf(8388608) | cos | sin | segcnt | segid
    float*  x    = ws;
    __bf16* qkvo = (__bf16*)(ws + BTD);
    __bf16* qb   = qkvo;
    __bf16* kb   = qkvo + BTD;
    __bf16* vb   = qkvo + 2 * BTD;
    __bf16* obuf = qkvo + 3 * BTD;
    __bf16* gbuf = qkvo;                    // overlay (post-attention phase)
    // segsum overlays x (dead after final rmsnorm). It needs Bq*(Tt+1)*Dd =
    // 4,196,352 floats — 2048 MORE than BTD, so it must NOT sit at ws+BTD
    // (that overran into hfin and zeroed its first 4 rows -> round-3 failure).
    float*  segsum = ws;
    float*  hfin   = ws + 2 * BTD;          // overlay (final norm out, fp32)
    __bf16* xnb  = (__bf16*)(ws + 3 * BTD);
    __bf16* wb   = (__bf16*)(ws + 3 * BTD + BTD / 2);
    float*  cosb = ws + 3 * BTD + BTD / 2 + 8388608;
    float*  sinb = cosb + (size_t)Tt * 32;
    float*  segcnt = sinb + (size_t)Tt * 32;
    int*    segid  = (int*)(segcnt + Bq * (Tt + 1));

    __bf16* wqb = wb;
    __bf16* wkb = wb + 1048576;
    __bf16* wvb = wb + 2097152;
    __bf16* wob = wb + 3145728;
    __bf16* w1b = wb + 4194304;
    __bf16* w3b = wb + 8388608;
    __bf16* w2b = wb + 12582912;

    // weight conversion fp32 -> bf16
    cvt_bf16_kernel<<<512, 256, 0, stream>>>(wq, wqb, 131072);
    cvt_bf16_kernel<<<512, 256, 0, stream>>>(wk, wkb, 131072);
    cvt_bf16_kernel<<<512, 256, 0, stream>>>(wv, wvb, 131072);
    cvt_bf16_kernel<<<512, 256, 0, stream>>>(wo, wob, 131072);
    cvt_bf16_kernel<<<2048, 256, 0, stream>>>(w1, w1b, 524288);
    cvt_bf16_kernel<<<2048, 256, 0, stream>>>(w3, w3b, 524288);
    cvt_bf16_kernel<<<2048, 256, 0, stream>>>(w2, w2b, 524288);

    embed_kernel<<<(int)((BTD / 4 + 255) / 256), 256, 0, stream>>>(tokens, embedw, x);
    rope_table_kernel<<<(Tt * 32 + 255) / 256, 256, 0, stream>>>(cosb, sinb);

    dim3 gq(4, 64);     // N=512
    dim3 gs(16, 64);    // N=2048
    dim3 ga(Tt / 64, Bq * Hh);
    int nrope = BT * 64;

    for (int l = 0; l < Ll; l++) {
        size_t oDD = (size_t)l * Dd * Dd;
        size_t oHD = (size_t)l * HIDN * Dd;
        rmsnorm_bf16_kernel<<<BT, 256, 0, stream>>>(x, attn_norm_w + (size_t)l * Dd, xnb);
        gemm_bt_mfma<0><<<gq, 256, 0, stream>>>(xnb, wqb + oDD, nullptr, qb, Dd, Dd);
        gemm_bt_mfma<0><<<gq, 256, 0, stream>>>(xnb, wkb + oDD, nullptr, kb, Dd, Dd);
        gemm_bt_mfma<0><<<gq, 256, 0, stream>>>(xnb, wvb + oDD, nullptr, vb, Dd, Dd);
        rope_bf16_kernel<true><<<(nrope + 255) / 256, 256, 0, stream>>>(qb, cosb, sinb);
        rope_bf16_kernel<false><<<(nrope + 255) / 256, 256, 0, stream>>>(kb, cosb, sinb);
        attn_mfma_kernel<<<ga, 256, 0, stream>>>(qb, kb, vb, obuf);
        gemm_bt_mfma<1><<<gq, 256, 0, stream>>>(obuf, wob + oDD, x, x, Dd, Dd);
        rmsnorm_bf16_kernel<<<BT, 256, 0, stream>>>(x, ffn_norm_w + (size_t)l * Dd, xnb);
        gemm_swiglu_mfma<<<gs, 256, 0, stream>>>(xnb, w1b + oHD, w3b + oHD, gbuf, HIDN, Dd);
        gemm_bt_mfma<1><<<gq, 256, 0, stream>>>(gbuf, w2b + oHD, x, x, Dd, HIDN);
    }

    rmsnorm_kernel<<<BT, 256, 0, stream>>>(x, final_norm_w, hfin);

    hipMemsetAsync(segsum, 0, (size_t)Bq * (Tt + 1) * Dd * sizeof(float), stream);
    hipMemsetAsync(segcnt, 0, (size_t)Bq * (Tt + 1) * sizeof(float), stream);
    seg_scan_kernel<<<Bq, 256, 0, stream>>>(tokens, segid);
    seg_cnt_kernel<<<(BT + 255) / 256, 256, 0, stream>>>(segid, segcnt);
    seg_accum_kernel<<<(int)((BTD + 255) / 256), 256, 0, stream>>>(hfin, segid, segsum);
    seg_final_kernel<<<(int)((BTD + 255) / 256), 256, 0, stream>>>(hfin, segsum, segcnt, segid, out);
}